// Round 1
// baseline (2109.340 us; speedup 1.0000x reference)
//
#include <hip/hip_runtime.h>

// LSTM(T=2048,B=256,IN=128,H=64) + FC(64). Three phases:
//  prep:   split W_ih into bf16 hi/lo, bias = b_ih + b_hh
//  phase1: xg[b][t][4H] = x@W_ih^T + bias  (bf16 MFMA, 3-term split precision)
//  lstm_seq: 1 block per batch element, 2048 serial steps, 1 barrier/step,
//            writes h into d_out ([t][b][64])
//  phase3: in-place FC on d_out
// xg stored fp32 in ws if ws_size permits (537 MB), else bf16 (269 MB).

#define T_STEPS 2048
#define BATCH   256
#define INSZ    128
#define HID     64
#define G4      256   // 4*HID

typedef __attribute__((ext_vector_type(8))) short bf16x8;
typedef __attribute__((ext_vector_type(4))) float f32x4;

__device__ __forceinline__ short f2bf(float f) {
  unsigned u = __float_as_uint(f);
  unsigned r = (u + 0x7fffu + ((u >> 16) & 1u)) >> 16;
  return (short)r;
}
__device__ __forceinline__ float bf2f(short s) {
  return __uint_as_float(((unsigned)(unsigned short)s) << 16);
}
__device__ __forceinline__ float xv(float v) { return v; }
__device__ __forceinline__ float xv(short v) { return bf2f(v); }
__device__ __forceinline__ void xg_store(float* p, long i, float v) { p[i] = v; }
__device__ __forceinline__ void xg_store(short* p, long i, float v) { p[i] = f2bf(v); }

#define LOG2E 1.44269504088896f
__device__ __forceinline__ float fast_sigmoid(float x) {
  float e = __builtin_amdgcn_exp2f(-LOG2E * x);
  return __builtin_amdgcn_rcpf(1.f + e);
}
__device__ __forceinline__ float fast_tanh(float x) {
  // 2*sigmoid(2x)-1; safe at both infinities (no inf-inf)
  float e = __builtin_amdgcn_exp2f(-2.f * LOG2E * x);
  return fmaf(2.f, __builtin_amdgcn_rcpf(1.f + e), -1.f);
}

__device__ __forceinline__ f32x4 mfma16(bf16x8 a, bf16x8 b, f32x4 c) {
  return __builtin_amdgcn_mfma_f32_16x16x32_bf16(a, b, c, 0, 0, 0);
}

// ---------------- prep: W_ih -> bf16 hi/lo, bias sum ----------------
__global__ void prep_kernel(const float* __restrict__ W_ih,
                            const float* __restrict__ b_ih,
                            const float* __restrict__ b_hh,
                            short* __restrict__ Whi, short* __restrict__ Wlo,
                            float* __restrict__ bias) {
  int i = blockIdx.x * 256 + threadIdx.x;  // grid covers exactly 256*128 = 32768
  float w = W_ih[i];
  short h = f2bf(w);
  Whi[i] = h;
  Wlo[i] = f2bf(w - bf2f(h));
  if (i < G4) bias[i] = b_ih[i] + b_hh[i];
}

// ---------------- phase 1: xg = x @ W_ih^T + bias (MFMA) ----------------
// block = 256 thr (4 waves); wave handles 32 rows (2 row-tiles of 16), all 256 cols.
// A-frags (x, split hi/lo) resident in regs; B (Whi/Wlo) loaded per 16-col tile.
template <typename XT>
__global__ __launch_bounds__(256, 2) void phase1_kernel(
    const float* __restrict__ x, const short* __restrict__ Whi,
    const short* __restrict__ Wlo, const float* __restrict__ bias,
    XT* __restrict__ xg) {
  int wave = threadIdx.x >> 6, lane = threadIdx.x & 63;
  int col = lane & 15, quad = lane >> 4;
  long rowbase = (long)blockIdx.x * 128 + wave * 32;

  bf16x8 Ah[2][4], Al[2][4];
#pragma unroll
  for (int rt = 0; rt < 2; ++rt) {
    const float* xp = x + (rowbase + rt * 16 + col) * INSZ + quad * 8;
#pragma unroll
    for (int kk = 0; kk < 4; ++kk) {
      float4 v0 = *(const float4*)(xp + kk * 32);
      float4 v1 = *(const float4*)(xp + kk * 32 + 4);
      bf16x8 hh, ll;
      float vv[8] = {v0.x, v0.y, v0.z, v0.w, v1.x, v1.y, v1.z, v1.w};
#pragma unroll
      for (int j = 0; j < 8; ++j) {
        short hb = f2bf(vv[j]);
        hh[j] = hb;
        ll[j] = f2bf(vv[j] - bf2f(hb));
      }
      Ah[rt][kk] = hh;
      Al[rt][kk] = ll;
    }
  }

#pragma unroll 1
  for (int gt = 0; gt < 16; ++gt) {
    int grow = gt * 16 + col;
    const short* bph = Whi + grow * INSZ + quad * 8;
    const short* bpl = Wlo + grow * INSZ + quad * 8;
    f32x4 acc0 = {0.f, 0.f, 0.f, 0.f}, acc1 = {0.f, 0.f, 0.f, 0.f};
#pragma unroll
    for (int kk = 0; kk < 4; ++kk) {
      bf16x8 bh = *(const bf16x8*)(bph + kk * 32);
      bf16x8 bl = *(const bf16x8*)(bpl + kk * 32);
      acc0 = mfma16(Ah[0][kk], bh, acc0);
      acc1 = mfma16(Ah[1][kk], bh, acc1);
      acc0 = mfma16(Al[0][kk], bh, acc0);
      acc1 = mfma16(Al[1][kk], bh, acc1);
      acc0 = mfma16(Ah[0][kk], bl, acc0);
      acc1 = mfma16(Ah[1][kk], bl, acc1);
    }
    float bv = bias[grow];
#pragma unroll
    for (int rt = 0; rt < 2; ++rt) {
      f32x4 a = rt ? acc1 : acc0;
#pragma unroll
      for (int r = 0; r < 4; ++r) {
        long m = rowbase + rt * 16 + quad * 4 + r;  // m = t*256 + b
        long bb = m & 255, tt = m >> 8;
        xg_store(xg, (bb * T_STEPS + tt) * G4 + grow, a[r] + bv);
      }
    }
  }
}

// ---------------- phase 2: sequential LSTM ----------------
// 256 blocks (1 per batch elem) x 256 threads. Thread g owns gate g.
// Per-wave h replica in LDS; gate-type exchange via double-buffered act LDS;
// ONE barrier per step; c/h update replicated across waves (lane j owns j).
template <typename XT>
__global__ __launch_bounds__(256, 1) void lstm_seq_kernel(
    const XT* __restrict__ xg, const float* __restrict__ W_hh,
    float* __restrict__ out) {
  int b = blockIdx.x, tid = threadIdx.x;
  int wave = tid >> 6, lane = tid & 63;
  __shared__ float hbuf[4][HID];      // per-wave private h replica
  __shared__ float abuf[2][G4];       // double-buffered activations

  // W_hh row g -> 64 VGPRs
  float4 wreg[16];
  const float4* wp = (const float4*)(W_hh + tid * HID);
#pragma unroll
  for (int i = 0; i < 16; ++i) wreg[i] = wp[i];

  float c = 0.f;
  hbuf[wave][lane] = 0.f;  // own replica; same-wave ordering suffices
  const float4* h4 = (const float4*)hbuf[wave];

  const XT* xp = xg + (size_t)b * T_STEPS * G4 + tid;
  // 4-deep prefetch pipeline for xg
  XT p0 = xp[0], p1 = xp[G4], p2 = xp[2 * G4], p3 = xp[3 * G4];

  for (int t = 0; t < T_STEPS; ++t) {
    float a0 = xv(p0), a1 = 0.f, a2 = 0.f, a3 = 0.f;
    p0 = p1; p1 = p2; p2 = p3;
    if (t + 4 < T_STEPS) p3 = xp[(size_t)(t + 4) * G4];

#pragma unroll
    for (int i = 0; i < 16; ++i) {
      float4 hv = h4[i];           // broadcast read, conflict-free
      float4 wv = wreg[i];
      a0 = fmaf(hv.x, wv.x, a0);
      a1 = fmaf(hv.y, wv.y, a1);
      a2 = fmaf(hv.z, wv.z, a2);
      a3 = fmaf(hv.w, wv.w, a3);
    }
    float a = (a0 + a1) + (a2 + a3);
    float actv = (wave == 2) ? fast_tanh(a) : fast_sigmoid(a);
    abuf[t & 1][tid] = actv;
    __syncthreads();
    const float* ab = abuf[t & 1];
    float iv = (wave == 0) ? actv : ab[lane];
    float fv = (wave == 1) ? actv : ab[HID + lane];
    float gv = (wave == 2) ? actv : ab[2 * HID + lane];
    float ov = (wave == 3) ? actv : ab[3 * HID + lane];
    c = fmaf(fv, c, iv * gv);
    float h = ov * fast_tanh(c);
    hbuf[wave][lane] = h;          // own replica for next step (no barrier)
    if (wave == 0) out[((size_t)t * BATCH + b) * HID + lane] = h;
  }
}

// ---------------- phase 3: in-place FC on d_out ----------------
// block = 256 thr handles 64 rows x 64 outs; thread (r=tid&63, q=tid>>6)
// computes outs [16q,16q+16) for row r.
__global__ __launch_bounds__(256) void fc_kernel(const float* __restrict__ W_fc,
                                                 const float* __restrict__ b_fc,
                                                 float* __restrict__ io) {
  __shared__ float hsl[64 * 65];  // padded: bank (r+k)%32, conflict-free
  __shared__ float wt[64 * 68];   // W^T[k][o], rows 16B-aligned for b128 bcast
  int tid = threadIdx.x;
  size_t base = (size_t)blockIdx.x * 4096;

#pragma unroll
  for (int i = 0; i < 16; ++i) {
    int flat = tid + i * 256;
    int r = flat >> 6, k = flat & 63;
    hsl[r * 65 + k] = io[base + flat];
  }
#pragma unroll
  for (int i = 0; i < 16; ++i) {
    int flat = tid + i * 256;
    int o = flat >> 6, k = flat & 63;
    wt[k * 68 + o] = W_fc[flat];
  }
  __syncthreads();

  int r = tid & 63, q = tid >> 6;
  float acc[16];
  const float4* bp = (const float4*)(b_fc + q * 16);
#pragma unroll
  for (int j = 0; j < 4; ++j) {
    float4 b4 = bp[j];
    acc[j * 4 + 0] = b4.x; acc[j * 4 + 1] = b4.y;
    acc[j * 4 + 2] = b4.z; acc[j * 4 + 3] = b4.w;
  }
#pragma unroll 4
  for (int k = 0; k < 64; ++k) {
    float hv = hsl[r * 65 + k];
    const float4* w4 = (const float4*)(wt + k * 68 + q * 16);
#pragma unroll
    for (int j = 0; j < 4; ++j) {
      float4 wv = w4[j];
      acc[j * 4 + 0] = fmaf(hv, wv.x, acc[j * 4 + 0]);
      acc[j * 4 + 1] = fmaf(hv, wv.y, acc[j * 4 + 1]);
      acc[j * 4 + 2] = fmaf(hv, wv.z, acc[j * 4 + 2]);
      acc[j * 4 + 3] = fmaf(hv, wv.w, acc[j * 4 + 3]);
    }
  }
  float* op = io + base + r * 64 + q * 16;
#pragma unroll
  for (int j = 0; j < 4; ++j) {
    *(float4*)(op + j * 4) = make_float4(acc[j * 4 + 0], acc[j * 4 + 1],
                                         acc[j * 4 + 2], acc[j * 4 + 3]);
  }
}

extern "C" void kernel_launch(void* const* d_in, const int* in_sizes, int n_in,
                              void* d_out, int out_size, void* d_ws, size_t ws_size,
                              hipStream_t stream) {
  const float* x    = (const float*)d_in[0];
  const float* W_ih = (const float*)d_in[1];
  const float* W_hh = (const float*)d_in[2];
  const float* b_ih = (const float*)d_in[3];
  const float* b_hh = (const float*)d_in[4];
  const float* W_fc = (const float*)d_in[5];
  const float* b_fc = (const float*)d_in[6];
  float* out = (float*)d_out;

  char* ws = (char*)d_ws;
  short* Whi  = (short*)ws;                 // 64 KB
  short* Wlo  = (short*)(ws + 65536);       // 64 KB
  float* bias = (float*)(ws + 131072);      // 1 KB
  void*  xgp  = (void*)(ws + 132096);

  size_t need_f32 = 132096 + (size_t)T_STEPS * BATCH * G4 * 4;
  bool use_f32 = ws_size >= need_f32;

  prep_kernel<<<128, 256, 0, stream>>>(W_ih, b_ih, b_hh, Whi, Wlo, bias);

  if (use_f32) {
    phase1_kernel<float><<<4096, 256, 0, stream>>>(x, Whi, Wlo, bias, (float*)xgp);
    lstm_seq_kernel<float><<<BATCH, 256, 0, stream>>>((const float*)xgp, W_hh, out);
  } else {
    phase1_kernel<short><<<4096, 256, 0, stream>>>(x, Whi, Wlo, bias, (short*)xgp);
    lstm_seq_kernel<short><<<BATCH, 256, 0, stream>>>((const short*)xgp, W_hh, out);
  }
  fc_kernel<<<8192, 256, 0, stream>>>(W_fc, b_fc, out);
}

// Round 2
// 1820.742 us; speedup vs baseline: 1.1585x; 1.1585x over previous
//
#include <hip/hip_runtime.h>

// LSTM(T=2048,B=256,IN=128,H=64) + FC(64).
//  prep:    split W_ih and W_fc into bf16 hi/lo, bias = b_ih + b_hh
//  phase1:  xg[t*B+b][4H] = x@W_ih^T + bias  (bf16 MFMA, 3-term split)
//  lstm_seq:1 block/batch elem, 2048 steps, raw-asm barrier (no vmcnt drain),
//           xg loads + h stores chunked per 8 steps, v_pk_fma_f32 inner loop
//  fc_mfma: in-place FC on d_out via bf16-split MFMA (no LDS)

#define T_STEPS 2048
#define BATCH   256
#define INSZ    128
#define HID     64
#define G4      256   // 4*HID

typedef __attribute__((ext_vector_type(8))) short bf16x8;
typedef __attribute__((ext_vector_type(4))) float f32x4;
typedef __attribute__((ext_vector_type(2))) float f32x2;

__device__ __forceinline__ short f2bf(float f) {
  unsigned u = __float_as_uint(f);
  unsigned r = (u + 0x7fffu + ((u >> 16) & 1u)) >> 16;
  return (short)r;
}
__device__ __forceinline__ float bf2f(short s) {
  return __uint_as_float(((unsigned)(unsigned short)s) << 16);
}

#define LOG2E 1.44269504088896f
__device__ __forceinline__ float fast_sigmoid(float x) {
  float e = __builtin_amdgcn_exp2f(-LOG2E * x);
  return __builtin_amdgcn_rcpf(1.f + e);
}
__device__ __forceinline__ float fast_tanh(float x) {
  float e = __builtin_amdgcn_exp2f(-2.f * LOG2E * x);
  return fmaf(2.f, __builtin_amdgcn_rcpf(1.f + e), -1.f);
}

__device__ __forceinline__ f32x4 mfma16(bf16x8 a, bf16x8 b, f32x4 c) {
  return __builtin_amdgcn_mfma_f32_16x16x32_bf16(a, b, c, 0, 0, 0);
}

// barrier WITHOUT the compiler's s_waitcnt vmcnt(0) drain (opaque to
// SIInsertWaitcnts). lgkmcnt(0) keeps cross-wave LDS ordering correct.
__device__ __forceinline__ void wave_barrier() {
  asm volatile("s_waitcnt lgkmcnt(0)\n\ts_barrier" ::: "memory");
}

__device__ __forceinline__ f32x2 pk_fma(f32x2 a, f32x2 b, f32x2 c) {
  f32x2 d;
  asm("v_pk_fma_f32 %0, %1, %2, %3" : "=v"(d) : "v"(a), "v"(b), "v"(c));
  return d;
}

// ---------------- prep: weight splits + bias sum ----------------
// grid 144*256 = 36864 = 32768 (W_ih) + 4096 (W_fc)
__global__ void prep_kernel(const float* __restrict__ W_ih,
                            const float* __restrict__ b_ih,
                            const float* __restrict__ b_hh,
                            const float* __restrict__ W_fc,
                            short* __restrict__ Whi, short* __restrict__ Wlo,
                            short* __restrict__ Fhi, short* __restrict__ Flo,
                            float* __restrict__ bias) {
  int i = blockIdx.x * 256 + threadIdx.x;
  if (i < 32768) {
    float w = W_ih[i];
    short h = f2bf(w);
    Whi[i] = h;
    Wlo[i] = f2bf(w - bf2f(h));
    if (i < G4) bias[i] = b_ih[i] + b_hh[i];
  } else {
    int j = i - 32768;
    float w = W_fc[j];
    short h = f2bf(w);
    Fhi[j] = h;
    Flo[j] = f2bf(w - bf2f(h));
  }
}

// ---------------- phase 1: xg = x @ W_ih^T + bias (MFMA) ----------------
// xg layout [m][g], m = t*B+b (natural row order of x — no transpose).
__global__ __launch_bounds__(256, 2) void phase1_kernel(
    const float* __restrict__ x, const short* __restrict__ Whi,
    const short* __restrict__ Wlo, const float* __restrict__ bias,
    short* __restrict__ xg) {
  int wave = threadIdx.x >> 6, lane = threadIdx.x & 63;
  int col = lane & 15, quad = lane >> 4;
  long rowbase = (long)blockIdx.x * 128 + wave * 32;

  bf16x8 Ah[2][4], Al[2][4];
#pragma unroll
  for (int rt = 0; rt < 2; ++rt) {
    const float* xp = x + (rowbase + rt * 16 + col) * INSZ + quad * 8;
#pragma unroll
    for (int kk = 0; kk < 4; ++kk) {
      float4 v0 = *(const float4*)(xp + kk * 32);
      float4 v1 = *(const float4*)(xp + kk * 32 + 4);
      bf16x8 hh, ll;
      float vv[8] = {v0.x, v0.y, v0.z, v0.w, v1.x, v1.y, v1.z, v1.w};
#pragma unroll
      for (int j = 0; j < 8; ++j) {
        short hb = f2bf(vv[j]);
        hh[j] = hb;
        ll[j] = f2bf(vv[j] - bf2f(hb));
      }
      Ah[rt][kk] = hh;
      Al[rt][kk] = ll;
    }
  }

#pragma unroll 1
  for (int gt = 0; gt < 16; ++gt) {
    int grow = gt * 16 + col;
    const short* bph = Whi + grow * INSZ + quad * 8;
    const short* bpl = Wlo + grow * INSZ + quad * 8;
    f32x4 acc0 = {0.f, 0.f, 0.f, 0.f}, acc1 = {0.f, 0.f, 0.f, 0.f};
#pragma unroll
    for (int kk = 0; kk < 4; ++kk) {
      bf16x8 bh = *(const bf16x8*)(bph + kk * 32);
      bf16x8 bl = *(const bf16x8*)(bpl + kk * 32);
      acc0 = mfma16(Ah[0][kk], bh, acc0);
      acc1 = mfma16(Ah[1][kk], bh, acc1);
      acc0 = mfma16(Al[0][kk], bh, acc0);
      acc1 = mfma16(Al[1][kk], bh, acc1);
      acc0 = mfma16(Ah[0][kk], bl, acc0);
      acc1 = mfma16(Ah[1][kk], bl, acc1);
    }
    float bv = bias[grow];
#pragma unroll
    for (int rt = 0; rt < 2; ++rt) {
      f32x4 a = rt ? acc1 : acc0;
#pragma unroll
      for (int r = 0; r < 4; ++r) {
        long m = rowbase + rt * 16 + quad * 4 + r;  // m = t*B + b
        xg[m * G4 + grow] = f2bf(a[r] + bv);
      }
    }
  }
}

// ---------------- phase 2: sequential LSTM ----------------
// 256 blocks (1/batch elem) x 256 thr. Thread g owns gate g. Per-wave h
// replica in LDS; activation exchange via double-buffered LDS + ONE raw-asm
// barrier per step; xg loads and h stores chunked per 8 steps so any forced
// drain is amortized 8x.
__global__ __launch_bounds__(256, 1) void lstm_seq_kernel(
    const short* __restrict__ xg, const float* __restrict__ W_hh,
    float* __restrict__ out) {
  int b = blockIdx.x, tid = threadIdx.x;
  int wave = tid >> 6, lane = tid & 63;
  __shared__ float hbuf[4][HID];
  __shared__ float abuf[2][G4];

  f32x2 wreg[32];
  const f32x2* wp = (const f32x2*)(W_hh + tid * HID);
#pragma unroll
  for (int i = 0; i < 32; ++i) wreg[i] = wp[i];

  float c = 0.f;
  hbuf[wave][lane] = 0.f;
  const f32x4* h4 = (const f32x4*)hbuf[wave];

  const short* xp = xg + (size_t)b * G4 + tid;  // + t*65536 per step
  short cur[8], nxt[8];
#pragma unroll
  for (int j = 0; j < 8; ++j) cur[j] = xp[(size_t)j * 65536];

  for (int chunk = 0; chunk < T_STEPS / 8; ++chunk) {
    int tb = chunk * 8;
    if (chunk < T_STEPS / 8 - 1) {
#pragma unroll
      for (int j = 0; j < 8; ++j) nxt[j] = xp[(size_t)(tb + 8 + j) * 65536];
    }
    float hout[8];
#pragma unroll
    for (int j = 0; j < 8; ++j) {
      f32x2 accA = {bf2f(cur[j]), 0.f};
      f32x2 accB = {0.f, 0.f}, accC = {0.f, 0.f}, accD = {0.f, 0.f};
#pragma unroll
      for (int i = 0; i < 16; i += 2) {
        f32x4 h0 = h4[i];
        f32x4 h1 = h4[i + 1];
        f32x2 h0lo = {h0.x, h0.y}, h0hi = {h0.z, h0.w};
        f32x2 h1lo = {h1.x, h1.y}, h1hi = {h1.z, h1.w};
        accA = pk_fma(h0lo, wreg[2 * i + 0], accA);
        accB = pk_fma(h0hi, wreg[2 * i + 1], accB);
        accC = pk_fma(h1lo, wreg[2 * i + 2], accC);
        accD = pk_fma(h1hi, wreg[2 * i + 3], accD);
      }
      f32x2 s = (accA + accB) + (accC + accD);
      float a = s.x + s.y;

      float actv = (wave == 2) ? fast_tanh(a) : fast_sigmoid(a);
      abuf[j & 1][tid] = actv;
      wave_barrier();
      const float* ab = abuf[j & 1];
      float iv = (wave == 0) ? actv : ab[lane];
      float fv = (wave == 1) ? actv : ab[HID + lane];
      float gv = (wave == 2) ? actv : ab[2 * HID + lane];
      float ov = (wave == 3) ? actv : ab[3 * HID + lane];
      c = fmaf(fv, c, iv * gv);
      float h = ov * fast_tanh(c);
      hbuf[wave][lane] = h;  // own replica; same-wave lgkm ordering suffices
      hout[j] = h;
    }
    if (wave == 0) {
#pragma unroll
      for (int j = 0; j < 8; ++j)
        out[((size_t)(tb + j) * BATCH + b) * HID + lane] = hout[j];
    }
#pragma unroll
    for (int j = 0; j < 8; ++j) cur[j] = nxt[j];
  }
}

// ---------------- phase 3: in-place FC via MFMA ----------------
// out[m][o] = sum_k hs[m][k] * W_fc[o][k] + b_fc[o]; K=64, N=64.
// block = 4 waves x 32 rows = 128 rows; each wave reads its own 32 rows into
// regs before storing the same rows — in-place safe, no LDS, no barrier.
__global__ __launch_bounds__(256, 2) void fc_mfma_kernel(
    float* io, const short* __restrict__ Fhi, const short* __restrict__ Flo,
    const float* __restrict__ b_fc) {
  int wave = threadIdx.x >> 6, lane = threadIdx.x & 63;
  int col = lane & 15, quad = lane >> 4;
  long rowbase = (long)blockIdx.x * 128 + wave * 32;

  bf16x8 Ah[2][2], Al[2][2];
#pragma unroll
  for (int rt = 0; rt < 2; ++rt) {
    const float* xp = io + (rowbase + rt * 16 + col) * HID + quad * 8;
#pragma unroll
    for (int kk = 0; kk < 2; ++kk) {
      float4 v0 = *(const float4*)(xp + kk * 32);
      float4 v1 = *(const float4*)(xp + kk * 32 + 4);
      bf16x8 hh, ll;
      float vv[8] = {v0.x, v0.y, v0.z, v0.w, v1.x, v1.y, v1.z, v1.w};
#pragma unroll
      for (int j = 0; j < 8; ++j) {
        short hb = f2bf(vv[j]);
        hh[j] = hb;
        ll[j] = f2bf(vv[j] - bf2f(hb));
      }
      Ah[rt][kk] = hh;
      Al[rt][kk] = ll;
    }
  }

#pragma unroll
  for (int gt = 0; gt < 4; ++gt) {
    int grow = gt * 16 + col;  // output index o
    const short* bph = Fhi + grow * HID + quad * 8;
    const short* bpl = Flo + grow * HID + quad * 8;
    f32x4 acc0 = {0.f, 0.f, 0.f, 0.f}, acc1 = {0.f, 0.f, 0.f, 0.f};
#pragma unroll
    for (int kk = 0; kk < 2; ++kk) {
      bf16x8 bh = *(const bf16x8*)(bph + kk * 32);
      bf16x8 bl = *(const bf16x8*)(bpl + kk * 32);
      acc0 = mfma16(Ah[0][kk], bh, acc0);
      acc1 = mfma16(Ah[1][kk], bh, acc1);
      acc0 = mfma16(Al[0][kk], bh, acc0);
      acc1 = mfma16(Al[1][kk], bh, acc1);
      acc0 = mfma16(Ah[0][kk], bl, acc0);
      acc1 = mfma16(Ah[1][kk], bl, acc1);
    }
    float bv = b_fc[grow];
#pragma unroll
    for (int rt = 0; rt < 2; ++rt) {
      f32x4 a = rt ? acc1 : acc0;
#pragma unroll
      for (int r = 0; r < 4; ++r) {
        long m = rowbase + rt * 16 + quad * 4 + r;
        io[m * HID + grow] = a[r] + bv;
      }
    }
  }
}

extern "C" void kernel_launch(void* const* d_in, const int* in_sizes, int n_in,
                              void* d_out, int out_size, void* d_ws, size_t ws_size,
                              hipStream_t stream) {
  const float* x    = (const float*)d_in[0];
  const float* W_ih = (const float*)d_in[1];
  const float* W_hh = (const float*)d_in[2];
  const float* b_ih = (const float*)d_in[3];
  const float* b_hh = (const float*)d_in[4];
  const float* W_fc = (const float*)d_in[5];
  const float* b_fc = (const float*)d_in[6];
  float* out = (float*)d_out;

  char* ws = (char*)d_ws;
  short* Whi  = (short*)ws;                 // 64 KB
  short* Wlo  = (short*)(ws + 65536);       // 64 KB
  short* Fhi  = (short*)(ws + 131072);      // 8 KB
  short* Flo  = (short*)(ws + 139264);      // 8 KB
  float* bias = (float*)(ws + 147456);      // 1 KB
  short* xg   = (short*)(ws + 148480);      // 268.4 MB (bf16 [T*B][4H])

  prep_kernel<<<144, 256, 0, stream>>>(W_ih, b_ih, b_hh, W_fc, Whi, Wlo, Fhi, Flo, bias);
  phase1_kernel<<<4096, 256, 0, stream>>>(x, Whi, Wlo, bias, xg);
  lstm_seq_kernel<<<BATCH, 256, 0, stream>>>(xg, W_hh, out);
  fc_mfma_kernel<<<4096, 256, 0, stream>>>(out, Fhi, Flo, b_fc);
}

// Round 3
// 1630.976 us; speedup vs baseline: 1.2933x; 1.1164x over previous
//
#include <hip/hip_runtime.h>

// LSTM(T=2048,B=256,IN=128,H=64) + FC(64).
//  prep:    split W_ih into bf16 hi/lo, bias = b_ih + b_hh
//  phase1:  xg[m=t*B+b][4H] = x@W_ih^T + bias  (bf16 MFMA, 3-term split)
//  lstm_fc: 1 WAVE per batch chain (256 blocks x 64 thr), NO barriers.
//           Lane j owns h[j]/c[j], computes all 4 gate dots via
//           v_dot2_f32_f16 on packed-f16 W_hh held in 128 VGPRs; h exchanged
//           intra-wave via f16 LDS broadcast. FC head fused (out written
//           one step late from the same broadcast reads).

#define T_STEPS 2048
#define BATCH   256
#define INSZ    128
#define HID     64
#define G4      256   // 4*HID

typedef __attribute__((ext_vector_type(8))) short bf16x8;
typedef __attribute__((ext_vector_type(4))) float f32x4;
typedef __attribute__((ext_vector_type(2))) _Float16 half2v;
typedef _Float16 __attribute__((may_alias)) half_a;

__device__ __forceinline__ short f2bf(float f) {
  unsigned u = __float_as_uint(f);
  unsigned r = (u + 0x7fffu + ((u >> 16) & 1u)) >> 16;
  return (short)r;
}
__device__ __forceinline__ float bf2f(short s) {
  return __uint_as_float(((unsigned)(unsigned short)s) << 16);
}
__device__ __forceinline__ float bf2f_u(unsigned short s) {
  return __uint_as_float(((unsigned)s) << 16);
}

#define LOG2E 1.44269504088896f
__device__ __forceinline__ float fast_sigmoid(float x) {
  float e = __builtin_amdgcn_exp2f(-LOG2E * x);
  return __builtin_amdgcn_rcpf(1.f + e);
}
__device__ __forceinline__ float fast_tanh(float x) {
  float e = __builtin_amdgcn_exp2f(-2.f * LOG2E * x);
  return fmaf(2.f, __builtin_amdgcn_rcpf(1.f + e), -1.f);
}

__device__ __forceinline__ f32x4 mfma16(bf16x8 a, bf16x8 b, f32x4 c) {
  return __builtin_amdgcn_mfma_f32_16x16x32_bf16(a, b, c, 0, 0, 0);
}

// f16 2-way dot with f32 accumulate: d = a.x*b.x + a.y*b.y + c
__device__ __forceinline__ float fdot2(unsigned hp, unsigned wp, float acc) {
#if __has_builtin(__builtin_amdgcn_fdot2)
  return __builtin_amdgcn_fdot2(__builtin_bit_cast(half2v, hp),
                                __builtin_bit_cast(half2v, wp), acc, false);
#else
  float d;
  asm("v_dot2_f32_f16 %0, %1, %2, %3" : "=v"(d) : "v"(hp), "v"(wp), "v"(acc));
  return d;
#endif
}
__device__ __forceinline__ unsigned pack_h2(float a, float b) {
  half2v p = {(_Float16)a, (_Float16)b};
  return __builtin_bit_cast(unsigned, p);
}

// ---------------- prep: W_ih bf16 hi/lo split + bias sum ----------------
__global__ void prep_kernel(const float* __restrict__ W_ih,
                            const float* __restrict__ b_ih,
                            const float* __restrict__ b_hh,
                            short* __restrict__ Whi, short* __restrict__ Wlo,
                            float* __restrict__ bias) {
  int i = blockIdx.x * 256 + threadIdx.x;  // 128 blocks cover 32768
  float w = W_ih[i];
  short h = f2bf(w);
  Whi[i] = h;
  Wlo[i] = f2bf(w - bf2f(h));
  if (i < G4) bias[i] = b_ih[i] + b_hh[i];
}

// ---------------- phase 1: xg = x @ W_ih^T + bias (MFMA) ----------------
__global__ __launch_bounds__(256, 2) void phase1_kernel(
    const float* __restrict__ x, const short* __restrict__ Whi,
    const short* __restrict__ Wlo, const float* __restrict__ bias,
    short* __restrict__ xg) {
  int wave = threadIdx.x >> 6, lane = threadIdx.x & 63;
  int col = lane & 15, quad = lane >> 4;
  long rowbase = (long)blockIdx.x * 128 + wave * 32;

  bf16x8 Ah[2][4], Al[2][4];
#pragma unroll
  for (int rt = 0; rt < 2; ++rt) {
    const float* xp = x + (rowbase + rt * 16 + col) * INSZ + quad * 8;
#pragma unroll
    for (int kk = 0; kk < 4; ++kk) {
      float4 v0 = *(const float4*)(xp + kk * 32);
      float4 v1 = *(const float4*)(xp + kk * 32 + 4);
      bf16x8 hh, ll;
      float vv[8] = {v0.x, v0.y, v0.z, v0.w, v1.x, v1.y, v1.z, v1.w};
#pragma unroll
      for (int j = 0; j < 8; ++j) {
        short hb = f2bf(vv[j]);
        hh[j] = hb;
        ll[j] = f2bf(vv[j] - bf2f(hb));
      }
      Ah[rt][kk] = hh;
      Al[rt][kk] = ll;
    }
  }

#pragma unroll 1
  for (int gt = 0; gt < 16; ++gt) {
    int grow = gt * 16 + col;
    const short* bph = Whi + grow * INSZ + quad * 8;
    const short* bpl = Wlo + grow * INSZ + quad * 8;
    f32x4 acc0 = {0.f, 0.f, 0.f, 0.f}, acc1 = {0.f, 0.f, 0.f, 0.f};
#pragma unroll
    for (int kk = 0; kk < 4; ++kk) {
      bf16x8 bh = *(const bf16x8*)(bph + kk * 32);
      bf16x8 bl = *(const bf16x8*)(bpl + kk * 32);
      acc0 = mfma16(Ah[0][kk], bh, acc0);
      acc1 = mfma16(Ah[1][kk], bh, acc1);
      acc0 = mfma16(Al[0][kk], bh, acc0);
      acc1 = mfma16(Al[1][kk], bh, acc1);
      acc0 = mfma16(Ah[0][kk], bl, acc0);
      acc1 = mfma16(Ah[1][kk], bl, acc1);
    }
    float bv = bias[grow];
#pragma unroll
    for (int rt = 0; rt < 2; ++rt) {
      f32x4 a = rt ? acc1 : acc0;
#pragma unroll
      for (int r = 0; r < 4; ++r) {
        long m = rowbase + rt * 16 + quad * 4 + r;  // m = t*B + b
        xg[m * G4 + grow] = f2bf(a[r] + bv);
      }
    }
  }
}

// ---------------- phase 2: LSTM recurrence + fused FC, 1 wave/chain -------
__global__ __launch_bounds__(64, 1) void lstm_fc_kernel(
    const short* __restrict__ xg, const float* __restrict__ W_hh,
    const float* __restrict__ W_fc, const float* __restrict__ b_fc,
    float* __restrict__ out) {
  int b = blockIdx.x, j = threadIdx.x;  // lane = hidden index
  __shared__ uint4 hbuf[2][8];          // packed f16 h, double-buffered

  // W_hh rows j, 64+j, 128+j, 192+j -> packed f16 (128 VGPRs)
  unsigned whh[4][32];
#pragma unroll
  for (int g = 0; g < 4; ++g) {
    const float* wr = W_hh + (g * HID + j) * HID;
#pragma unroll
    for (int k = 0; k < 32; ++k) whh[g][k] = pack_h2(wr[2 * k], wr[2 * k + 1]);
  }
  // W_fc row j (lane = output index o for the FC head), packed f16
  unsigned wfc[32];
  {
    const float* fr = W_fc + j * HID;
#pragma unroll
    for (int k = 0; k < 32; ++k) wfc[k] = pack_h2(fr[2 * k], fr[2 * k + 1]);
  }
  float bfc = b_fc[j];

  if (j < 8) hbuf[0][j] = make_uint4(0, 0, 0, 0);  // h_{-1} = 0 (own wave)

  const unsigned short* xq = (const unsigned short*)xg + (size_t)b * G4 + j;
  const unsigned short* pf = xq + 2 * (size_t)(BATCH * G4);
  unsigned short L0[4], L1[4];
#pragma unroll
  for (int g = 0; g < 4; ++g) {
    L0[g] = xq[g * HID];
    L1[g] = xq[(size_t)(BATCH * G4) + g * HID];
  }

  float* op = out + (size_t)b * HID + j;  // row t-1 written at iter t
  float c = 0.f;

  for (int t = 0; t < T_STEPS; ++t) {
    // gate biases for this step (xg holds x@W_ih^T + b_ih + b_hh)
    float a0 = bf2f_u(L0[0]), a1 = bf2f_u(L0[1]);
    float a2 = bf2f_u(L0[2]), a3 = bf2f_u(L0[3]);

    // broadcast h_{t-1} (packed f16) — all lanes same address, conflict-free
    const uint4* hb = hbuf[t & 1];
    unsigned hp[32];
#pragma unroll
    for (int i = 0; i < 8; ++i) {
      uint4 v = hb[i];
      hp[4 * i + 0] = v.x; hp[4 * i + 1] = v.y;
      hp[4 * i + 2] = v.z; hp[4 * i + 3] = v.w;
    }

    // 4 gate dot products, K=64 (interleaved chains: issue-bound, not latency)
#pragma unroll
    for (int k = 0; k < 32; ++k) {
      a0 = fdot2(hp[k], whh[0][k], a0);
      a1 = fdot2(hp[k], whh[1][k], a1);
      a2 = fdot2(hp[k], whh[2][k], a2);
      a3 = fdot2(hp[k], whh[3][k], a3);
    }

    // rotate xg pipeline (depth 2 ≈ 2 steps of HBM-latency slack)
#pragma unroll
    for (int g = 0; g < 4; ++g) L0[g] = L1[g];
    if (t + 2 < T_STEPS) {
#pragma unroll
      for (int g = 0; g < 4; ++g) L1[g] = pf[g * HID];
      pf += BATCH * G4;
    }

    float iv = fast_sigmoid(a0);
    float fv = fast_sigmoid(a1);
    float gv = fast_tanh(a2);
    float ov = fast_sigmoid(a3);
    c = fmaf(fv, c, iv * gv);
    float h = ov * fast_tanh(c);

    // publish h_t for next step (f16, own lane; same-wave DS ordering)
    ((half_a*)hbuf[(t + 1) & 1])[j] = (_Float16)h;

    // fused FC on h_{t-1} (reuses hp; scheduled after h-write to cover
    // the LDS write->read latency of the next step)
    float f0 = 0.f, f1 = 0.f, f2 = 0.f, f3 = 0.f;
#pragma unroll
    for (int k = 0; k < 8; ++k) {
      f0 = fdot2(hp[4 * k + 0], wfc[4 * k + 0], f0);
      f1 = fdot2(hp[4 * k + 1], wfc[4 * k + 1], f1);
      f2 = fdot2(hp[4 * k + 2], wfc[4 * k + 2], f2);
      f3 = fdot2(hp[4 * k + 3], wfc[4 * k + 3], f3);
    }
    if (t > 0) {
      op[0] = ((f0 + f1) + (f2 + f3)) + bfc;
      op += BATCH * HID;
    }
  }

  // tail: FC on h_{T-1}
  {
    const uint4* hb = hbuf[T_STEPS & 1];
    float f0 = 0.f, f1 = 0.f, f2 = 0.f, f3 = 0.f;
#pragma unroll
    for (int i = 0; i < 8; ++i) {
      uint4 v = hb[i];
      f0 = fdot2(v.x, wfc[4 * i + 0], f0);
      f1 = fdot2(v.y, wfc[4 * i + 1], f1);
      f2 = fdot2(v.z, wfc[4 * i + 2], f2);
      f3 = fdot2(v.w, wfc[4 * i + 3], f3);
    }
    op[0] = ((f0 + f1) + (f2 + f3)) + bfc;
  }
}

extern "C" void kernel_launch(void* const* d_in, const int* in_sizes, int n_in,
                              void* d_out, int out_size, void* d_ws, size_t ws_size,
                              hipStream_t stream) {
  const float* x    = (const float*)d_in[0];
  const float* W_ih = (const float*)d_in[1];
  const float* W_hh = (const float*)d_in[2];
  const float* b_ih = (const float*)d_in[3];
  const float* b_hh = (const float*)d_in[4];
  const float* W_fc = (const float*)d_in[5];
  const float* b_fc = (const float*)d_in[6];
  float* out = (float*)d_out;

  char* ws = (char*)d_ws;
  short* Whi  = (short*)ws;                 // 64 KB
  short* Wlo  = (short*)(ws + 65536);       // 64 KB
  float* bias = (float*)(ws + 131072);      // 1 KB
  short* xg   = (short*)(ws + 132096);      // 268.4 MB bf16 [T*B][4H]

  prep_kernel<<<128, 256, 0, stream>>>(W_ih, b_ih, b_hh, Whi, Wlo, bias);
  phase1_kernel<<<4096, 256, 0, stream>>>(x, Whi, Wlo, bias, xg);
  lstm_fc_kernel<<<BATCH, 64, 0, stream>>>(xg, W_hh, W_fc, b_fc, out);
}